// Round 1
// baseline (1095.095 us; speedup 1.0000x reference)
//
#include <hip/hip_runtime.h>

#define NN 50000
#define NE 500000
#define HD 128
#define HD2 256
#define NL 4
#define NG 1000

constexpr float MSG_EPS = 1e-7f;
constexpr float LNEPS   = 1e-5f;

// ---------------- node encoder: h = x @ Wn + bn ----------------
__global__ void k_encode_nodes(const float* __restrict__ x, const float* __restrict__ W,
                               const float* __restrict__ b, float* __restrict__ h) {
    int n = blockIdx.x;
    int c = threadIdx.x;  // 128
    float xr[9];
#pragma unroll
    for (int k = 0; k < 9; k++) xr[k] = x[n * 9 + k];
    float acc = b[c];
#pragma unroll
    for (int k = 0; k < 9; k++) acc = fmaf(xr[k], W[k * HD + c], acc);
    h[n * HD + c] = acc;
}

// ---------------- CSR build ----------------
__global__ void k_hist(const int* __restrict__ dst, int* __restrict__ counts) {
    int e = blockIdx.x * blockDim.x + threadIdx.x;
    if (e < NE) atomicAdd(&counts[dst[e]], 1);
}

#define SCAN_B 512
__global__ void k_scan1(const int* __restrict__ counts, int* __restrict__ incl,
                        int* __restrict__ bsum) {
    __shared__ int s[SCAN_B];
    int i = blockIdx.x * SCAN_B + threadIdx.x;
    int v = (i < NN) ? counts[i] : 0;
    s[threadIdx.x] = v;
    __syncthreads();
    for (int off = 1; off < SCAN_B; off <<= 1) {
        int t = (threadIdx.x >= off) ? s[threadIdx.x - off] : 0;
        __syncthreads();
        s[threadIdx.x] += t;
        __syncthreads();
    }
    if (i < NN) incl[i] = s[threadIdx.x];
    if (threadIdx.x == SCAN_B - 1) bsum[blockIdx.x] = s[threadIdx.x];
}

__global__ void k_scan2(const int* __restrict__ bsum, int* __restrict__ boff, int nb) {
    __shared__ int s[128];
    int v = (threadIdx.x < nb) ? bsum[threadIdx.x] : 0;
    s[threadIdx.x] = v;
    __syncthreads();
    for (int off = 1; off < 128; off <<= 1) {
        int t = (threadIdx.x >= off) ? s[threadIdx.x - off] : 0;
        __syncthreads();
        s[threadIdx.x] += t;
        __syncthreads();
    }
    if (threadIdx.x < nb) boff[threadIdx.x] = s[threadIdx.x] - v;  // exclusive
}

__global__ void k_scan3(const int* __restrict__ incl, const int* __restrict__ boff,
                        int* __restrict__ row_start) {
    int i = blockIdx.x * SCAN_B + threadIdx.x;
    if (i < NN) row_start[i + 1] = incl[i] + boff[blockIdx.x];
    if (i == 0) row_start[0] = 0;
}

// pack {attr0, attr1, attr2, src} per CSR slot
__global__ void k_scatter(const int* __restrict__ src, const int* __restrict__ dst,
                          const float* __restrict__ eattr, const int* __restrict__ row_start,
                          int* __restrict__ cursor, float4* __restrict__ aperm) {
    int e = blockIdx.x * blockDim.x + threadIdx.x;
    if (e >= NE) return;
    int d = dst[e];
    int p = row_start[d] + atomicAdd(&cursor[d], 1);
    float4 v;
    v.x = eattr[e * 3 + 0];
    v.y = eattr[e * 3 + 1];
    v.z = eattr[e * 3 + 2];
    v.w = __int_as_float(src[e]);
    aperm[p] = v;
}

// ---------------- LN + relu over 128 channels (one wave per node) ----------------
__global__ void k_ln_relu(const float* __restrict__ h, const float* __restrict__ g,
                          const float* __restrict__ b, float* __restrict__ z) {
    int wave = threadIdx.x >> 6;
    int lane = threadIdx.x & 63;
    int n = blockIdx.x * 4 + wave;
    if (n >= NN) return;
    float v0 = h[n * HD + lane], v1 = h[n * HD + 64 + lane];
    float s = v0 + v1, sq = v0 * v0 + v1 * v1;
#pragma unroll
    for (int m = 32; m >= 1; m >>= 1) {
        s += __shfl_xor(s, m);
        sq += __shfl_xor(sq, m);
    }
    float mu = s * (1.f / 128.f);
    float var = sq * (1.f / 128.f) - mu * mu;
    float inv = rsqrtf(var + LNEPS);
    float z0 = fmaf((v0 - mu) * inv, g[lane], b[lane]);
    float z1 = fmaf((v1 - mu) * inv, g[64 + lane], b[64 + lane]);
    z[n * HD + lane] = fmaxf(z0, 0.f);
    z[n * HD + 64 + lane] = fmaxf(z1, 0.f);
}

// ---------------- softmax aggregation (block = 1 dst node, 128 threads) ----------------
// agg = sum(msg * exp(t*msg)) / sum(exp(t*msg));  out = agg + z[n]
__global__ void k_aggregate(const float* __restrict__ z, const float4* __restrict__ aperm,
                            const int* __restrict__ row_start, const float* __restrict__ We,
                            const float* __restrict__ be, const float* __restrict__ t, int layer,
                            float* __restrict__ outb) {
    int n = blockIdx.x;
    int c = threadIdx.x;
    float w0 = We[c], w1 = We[HD + c], w2 = We[2 * HD + c], bb = be[c];
    float tv = t[layer];
    int s0 = row_start[n], s1 = row_start[n + 1];
    float num = 0.f, wm = 0.f;
    for (int p = s0; p < s1; p++) {
        float4 a = aperm[p];
        int sj = __float_as_int(a.w);
        float ea = fmaf(a.x, w0, fmaf(a.y, w1, fmaf(a.z, w2, bb)));
        float msg = fmaxf(z[sj * HD + c] + ea, 0.f) + MSG_EPS;
        float ex = __expf(tv * msg);
        num += ex;
        wm = fmaf(msg, ex, wm);
    }
    float agg = (s1 > s0) ? (wm / num) : 0.f;
    outb[n * HD + c] = agg + z[n * HD + c];
}

// ---------------- fused MLP: y = relu(LN(A@W1+b1))@W2 + b2 ; h = (add? h+y : y) --------
// block: 256 threads, BM=32 nodes.  half = tid>>7 picks 16 rows, j = tid&127 picks cols.
#define BM 32
__global__ __launch_bounds__(256) void k_mlp(const float* __restrict__ outb,
                                             const float* __restrict__ W1l,
                                             const float* __restrict__ b1l,
                                             const float* __restrict__ lgl,
                                             const float* __restrict__ lbl,
                                             const float* __restrict__ W2l,
                                             const float* __restrict__ b2l,
                                             float* __restrict__ h, int add_residual) {
    __shared__ float As[BM][HD];    // 16 KB
    __shared__ float Hs[BM][HD2];   // 32 KB
    int nb = blockIdx.x * BM;
    int tid = threadIdx.x;
    int rows = NN - nb;
    if (rows > BM) rows = BM;

    // stage A tile
    for (int i = tid; i < BM * HD / 4; i += 256) {
        int r = i / (HD / 4);
        int c4 = i % (HD / 4);
        float4 v = make_float4(0.f, 0.f, 0.f, 0.f);
        if (r < rows) v = ((const float4*)(outb + (size_t)(nb + r) * HD))[c4];
        ((float4*)&As[r][0])[c4] = v;
    }
    __syncthreads();

    int half = tid >> 7;   // row group: half*16 .. half*16+15
    int j = tid & 127;     // column (and j+128 in GEMM1)
    int r0 = half * 16;

    // GEMM1: 16 rows x 2 cols per thread
    float acc[16][2];
#pragma unroll
    for (int m = 0; m < 16; m++) {
        acc[m][0] = b1l[j];
        acc[m][1] = b1l[j + 128];
    }
    for (int k = 0; k < HD; k += 4) {
        float wa0 = W1l[(k + 0) * HD2 + j], wb0 = W1l[(k + 0) * HD2 + j + 128];
        float wa1 = W1l[(k + 1) * HD2 + j], wb1 = W1l[(k + 1) * HD2 + j + 128];
        float wa2 = W1l[(k + 2) * HD2 + j], wb2 = W1l[(k + 2) * HD2 + j + 128];
        float wa3 = W1l[(k + 3) * HD2 + j], wb3 = W1l[(k + 3) * HD2 + j + 128];
#pragma unroll
        for (int m = 0; m < 16; m++) {
            float4 a = *(const float4*)&As[r0 + m][k];
            acc[m][0] = fmaf(a.x, wa0, acc[m][0]);
            acc[m][0] = fmaf(a.y, wa1, acc[m][0]);
            acc[m][0] = fmaf(a.z, wa2, acc[m][0]);
            acc[m][0] = fmaf(a.w, wa3, acc[m][0]);
            acc[m][1] = fmaf(a.x, wb0, acc[m][1]);
            acc[m][1] = fmaf(a.y, wb1, acc[m][1]);
            acc[m][1] = fmaf(a.z, wb2, acc[m][1]);
            acc[m][1] = fmaf(a.w, wb3, acc[m][1]);
        }
    }
#pragma unroll
    for (int m = 0; m < 16; m++) {
        Hs[r0 + m][j] = acc[m][0];
        Hs[r0 + m][j + 128] = acc[m][1];
    }
    __syncthreads();

    // LN(256) + relu, one wave per row
    {
        int wave = tid >> 6, lane = tid & 63;
        float g0 = lgl[lane], g1 = lgl[lane + 64], g2 = lgl[lane + 128], g3 = lgl[lane + 192];
        float c0 = lbl[lane], c1 = lbl[lane + 64], c2 = lbl[lane + 128], c3 = lbl[lane + 192];
        for (int rr = wave; rr < BM; rr += 4) {
            float v0 = Hs[rr][lane], v1 = Hs[rr][lane + 64];
            float v2 = Hs[rr][lane + 128], v3 = Hs[rr][lane + 192];
            float s = v0 + v1 + v2 + v3;
            float sq = v0 * v0 + v1 * v1 + v2 * v2 + v3 * v3;
#pragma unroll
            for (int m = 32; m >= 1; m >>= 1) {
                s += __shfl_xor(s, m);
                sq += __shfl_xor(sq, m);
            }
            float mu = s * (1.f / 256.f);
            float var = sq * (1.f / 256.f) - mu * mu;
            float inv = rsqrtf(var + LNEPS);
            Hs[rr][lane] = fmaxf(fmaf((v0 - mu) * inv, g0, c0), 0.f);
            Hs[rr][lane + 64] = fmaxf(fmaf((v1 - mu) * inv, g1, c1), 0.f);
            Hs[rr][lane + 128] = fmaxf(fmaf((v2 - mu) * inv, g2, c2), 0.f);
            Hs[rr][lane + 192] = fmaxf(fmaf((v3 - mu) * inv, g3, c3), 0.f);
        }
    }
    __syncthreads();

    // GEMM2: 16 rows x 1 col per thread, K=256
    float acc2[16];
#pragma unroll
    for (int m = 0; m < 16; m++) acc2[m] = b2l[j];
    for (int k = 0; k < HD2; k += 4) {
        float w0 = W2l[(k + 0) * HD + j];
        float w1 = W2l[(k + 1) * HD + j];
        float w2 = W2l[(k + 2) * HD + j];
        float w3 = W2l[(k + 3) * HD + j];
#pragma unroll
        for (int m = 0; m < 16; m++) {
            float4 a = *(const float4*)&Hs[r0 + m][k];
            acc2[m] = fmaf(a.x, w0, acc2[m]);
            acc2[m] = fmaf(a.y, w1, acc2[m]);
            acc2[m] = fmaf(a.z, w2, acc2[m]);
            acc2[m] = fmaf(a.w, w3, acc2[m]);
        }
    }
#pragma unroll
    for (int m = 0; m < 16; m++) {
        int row = nb + r0 + m;
        if (row < NN) {
            size_t idx = (size_t)row * HD + j;
            h[idx] = add_residual ? (h[idx] + acc2[m]) : acc2[m];
        }
    }
}

// ---------------- global mean pool ----------------
__global__ void k_pool_accum(const float* __restrict__ z, const int* __restrict__ batch,
                             float* __restrict__ sums, float* __restrict__ cnt) {
    int n = blockIdx.x;
    int c = threadIdx.x;
    int g = batch[n];
    atomicAdd(&sums[g * HD + c], z[n * HD + c]);
    if (c == 0) atomicAdd(&cnt[g], 1.0f);
}

__global__ void k_pool_final(const float* __restrict__ sums, const float* __restrict__ cnt,
                             float* __restrict__ out) {
    int g = blockIdx.x;
    int c = threadIdx.x;
    out[g * HD + c] = sums[g * HD + c] / fmaxf(cnt[g], 1.0f);
}

// ---------------- launch ----------------
extern "C" void kernel_launch(void* const* d_in, const int* in_sizes, int n_in, void* d_out,
                              int out_size, void* d_ws, size_t ws_size, hipStream_t stream) {
    const float* x     = (const float*)d_in[0];
    const int* ei      = (const int*)d_in[1];
    const float* eattr = (const float*)d_in[2];
    const int* batch   = (const int*)d_in[3];
    const float* encW  = (const float*)d_in[4];
    const float* encB  = (const float*)d_in[5];
    const float* eW    = (const float*)d_in[6];
    const float* eB    = (const float*)d_in[7];
    const float* ln_g  = (const float*)d_in[8];
    const float* ln_b  = (const float*)d_in[9];
    const float* W1    = (const float*)d_in[10];
    const float* b1    = (const float*)d_in[11];
    const float* mlg   = (const float*)d_in[12];
    const float* mlb   = (const float*)d_in[13];
    const float* W2    = (const float*)d_in[14];
    const float* b2    = (const float*)d_in[15];
    const float* t     = (const float*)d_in[16];
    const int* src = ei;
    const int* dst = ei + NE;

    char* w = (char*)d_ws;
    auto alloc = [&](size_t bytes) {
        char* p = w;
        w += (bytes + 255) & ~size_t(255);
        return p;
    };
    float* h        = (float*)alloc(sizeof(float) * NN * HD);
    float* z        = (float*)alloc(sizeof(float) * NN * HD);
    float* outb     = (float*)alloc(sizeof(float) * NN * HD);
    float4* aperm   = (float4*)alloc(sizeof(float4) * NE);
    int* row_start  = (int*)alloc(sizeof(int) * (NN + 1));
    int* counts     = (int*)alloc(sizeof(int) * NN);
    int* cursor     = (int*)alloc(sizeof(int) * NN);
    int* incl       = (int*)alloc(sizeof(int) * NN);
    int* bsum       = (int*)alloc(sizeof(int) * 128);
    int* boff       = (int*)alloc(sizeof(int) * 128);
    float* sums     = (float*)alloc(sizeof(float) * NG * HD);
    float* cnt      = (float*)alloc(sizeof(float) * NG);

    hipMemsetAsync(counts, 0, sizeof(int) * NN, stream);
    hipMemsetAsync(cursor, 0, sizeof(int) * NN, stream);
    hipMemsetAsync(sums, 0, sizeof(float) * NG * HD, stream);
    hipMemsetAsync(cnt, 0, sizeof(float) * NG, stream);

    k_encode_nodes<<<NN, HD, 0, stream>>>(x, encW, encB, h);
    k_hist<<<(NE + 255) / 256, 256, 0, stream>>>(dst, counts);
    int nsb = (NN + SCAN_B - 1) / SCAN_B;
    k_scan1<<<nsb, SCAN_B, 0, stream>>>(counts, incl, bsum);
    k_scan2<<<1, 128, 0, stream>>>(bsum, boff, nsb);
    k_scan3<<<nsb, SCAN_B, 0, stream>>>(incl, boff, row_start);
    k_scatter<<<(NE + 255) / 256, 256, 0, stream>>>(src, dst, eattr, row_start, cursor, aperm);

    for (int l = 0; l < NL; l++) {
        const float* zin;
        if (l == 0) {
            zin = h;
        } else {
            k_ln_relu<<<NN / 4, 256, 0, stream>>>(h, ln_g + l * HD, ln_b + l * HD, z);
            zin = z;
        }
        k_aggregate<<<NN, HD, 0, stream>>>(zin, aperm, row_start, eW, eB, t, l, outb);
        k_mlp<<<(NN + BM - 1) / BM, 256, 0, stream>>>(outb, W1 + (size_t)l * HD * HD2,
                                                      b1 + l * HD2, mlg + l * HD2, mlb + l * HD2,
                                                      W2 + (size_t)l * HD2 * HD, b2 + l * HD, h,
                                                      l > 0);
    }
    k_ln_relu<<<NN / 4, 256, 0, stream>>>(h, ln_g, ln_b, z);  // reuses layer-0 norm
    k_pool_accum<<<NN, HD, 0, stream>>>(z, batch, sums, cnt);
    k_pool_final<<<NG, HD, 0, stream>>>(sums, cnt, (float*)d_out);
}

// Round 2
// 712.697 us; speedup vs baseline: 1.5365x; 1.5365x over previous
//
#include <hip/hip_runtime.h>

#define NN 50000
#define NE 500000
#define HD 128
#define HD2 256
#define NL 4
#define NG 1000

constexpr float MSG_EPS = 1e-7f;
constexpr float LNEPS   = 1e-5f;

typedef float  f32x4  __attribute__((ext_vector_type(4)));
typedef __bf16 bf16x8 __attribute__((ext_vector_type(8)));

__device__ __forceinline__ unsigned short f2b(float f) {
    unsigned int u = __float_as_uint(f);
    unsigned int r = u + 0x7FFFu + ((u >> 16) & 1u);
    return (unsigned short)(r >> 16);
}
__device__ __forceinline__ float b2f(unsigned short h) {
    return __uint_as_float(((unsigned int)h) << 16);
}

// ---------------- node encoder: h = x @ Wn + bn ----------------
__global__ void k_encode_nodes(const float* __restrict__ x, const float* __restrict__ W,
                               const float* __restrict__ b, float* __restrict__ h) {
    int n = blockIdx.x;
    int c = threadIdx.x;  // 128
    float xr[9];
#pragma unroll
    for (int k = 0; k < 9; k++) xr[k] = x[n * 9 + k];
    float acc = b[c];
#pragma unroll
    for (int k = 0; k < 9; k++) acc = fmaf(xr[k], W[k * HD + c], acc);
    h[n * HD + c] = acc;
}

// ---------------- weight prep: fp32 -> bf16 transposed ----------------
// W1 [L][128][256] -> W1T [L][256][128];  W2 [L][256][128] -> W2T [L][128][256]
__global__ void k_prep(const float* __restrict__ W1, const float* __restrict__ W2,
                       unsigned short* __restrict__ W1T, unsigned short* __restrict__ W2T) {
    int idx = blockIdx.x * 256 + threadIdx.x;  // 131072 total
    {
        int k = idx & 127, n = (idx >> 7) & 255, l = idx >> 15;
        W1T[idx] = f2b(W1[(l * 128 + k) * 256 + n]);
    }
    {
        int k = idx & 255, n = (idx >> 8) & 127, l = idx >> 15;
        W2T[idx] = f2b(W2[(l * 256 + k) * 128 + n]);
    }
}

// ---------------- CSR build ----------------
__global__ void k_hist(const int* __restrict__ dst, int* __restrict__ counts) {
    int e = blockIdx.x * blockDim.x + threadIdx.x;
    if (e < NE) atomicAdd(&counts[dst[e]], 1);
}

#define SCAN_B 512
__global__ void k_scan1(const int* __restrict__ counts, int* __restrict__ incl,
                        int* __restrict__ bsum) {
    __shared__ int s[SCAN_B];
    int i = blockIdx.x * SCAN_B + threadIdx.x;
    int v = (i < NN) ? counts[i] : 0;
    s[threadIdx.x] = v;
    __syncthreads();
    for (int off = 1; off < SCAN_B; off <<= 1) {
        int t = (threadIdx.x >= off) ? s[threadIdx.x - off] : 0;
        __syncthreads();
        s[threadIdx.x] += t;
        __syncthreads();
    }
    if (i < NN) incl[i] = s[threadIdx.x];
    if (threadIdx.x == SCAN_B - 1) bsum[blockIdx.x] = s[threadIdx.x];
}

__global__ void k_scan2(const int* __restrict__ bsum, int* __restrict__ boff, int nb) {
    __shared__ int s[128];
    int v = (threadIdx.x < nb) ? bsum[threadIdx.x] : 0;
    s[threadIdx.x] = v;
    __syncthreads();
    for (int off = 1; off < 128; off <<= 1) {
        int t = (threadIdx.x >= off) ? s[threadIdx.x - off] : 0;
        __syncthreads();
        s[threadIdx.x] += t;
        __syncthreads();
    }
    if (threadIdx.x < nb) boff[threadIdx.x] = s[threadIdx.x] - v;  // exclusive
}

__global__ void k_scan3(const int* __restrict__ incl, const int* __restrict__ boff,
                        int* __restrict__ row_start) {
    int i = blockIdx.x * SCAN_B + threadIdx.x;
    if (i < NN) row_start[i + 1] = incl[i] + boff[blockIdx.x];
    if (i == 0) row_start[0] = 0;
}

// pack {attr0, attr1, attr2, src} per CSR slot
__global__ void k_scatter(const int* __restrict__ src, const int* __restrict__ dst,
                          const float* __restrict__ eattr, const int* __restrict__ row_start,
                          int* __restrict__ cursor, float4* __restrict__ aperm) {
    int e = blockIdx.x * blockDim.x + threadIdx.x;
    if (e >= NE) return;
    int d = dst[e];
    int p = row_start[d] + atomicAdd(&cursor[d], 1);
    float4 v;
    v.x = eattr[e * 3 + 0];
    v.y = eattr[e * 3 + 1];
    v.z = eattr[e * 3 + 2];
    v.w = __int_as_float(src[e]);
    aperm[p] = v;
}

// ---------------- LN + relu over 128 channels (one wave per node) ----------------
__global__ void k_ln_relu(const float* __restrict__ h, const float* __restrict__ g,
                          const float* __restrict__ b, float* __restrict__ z) {
    int wave = threadIdx.x >> 6;
    int lane = threadIdx.x & 63;
    int n = blockIdx.x * 4 + wave;
    if (n >= NN) return;
    float v0 = h[n * HD + lane], v1 = h[n * HD + 64 + lane];
    float s = v0 + v1, sq = v0 * v0 + v1 * v1;
#pragma unroll
    for (int m = 32; m >= 1; m >>= 1) {
        s += __shfl_xor(s, m);
        sq += __shfl_xor(sq, m);
    }
    float mu = s * (1.f / 128.f);
    float var = sq * (1.f / 128.f) - mu * mu;
    float inv = rsqrtf(var + LNEPS);
    float z0 = fmaf((v0 - mu) * inv, g[lane], b[lane]);
    float z1 = fmaf((v1 - mu) * inv, g[64 + lane], b[64 + lane]);
    z[n * HD + lane] = fmaxf(z0, 0.f);
    z[n * HD + 64 + lane] = fmaxf(z1, 0.f);
}

// ---------------- softmax aggregation (block = 1 dst node, 128 threads) ----------------
__global__ void k_aggregate(const float* __restrict__ z, const float4* __restrict__ aperm,
                            const int* __restrict__ row_start, const float* __restrict__ We,
                            const float* __restrict__ be, const float* __restrict__ t, int layer,
                            float* __restrict__ outb) {
    int n = blockIdx.x;
    int c = threadIdx.x;
    float w0 = We[c], w1 = We[HD + c], w2 = We[2 * HD + c], bb = be[c];
    float tv = t[layer];
    int s0 = row_start[n], s1 = row_start[n + 1];
    float num = 0.f, wm = 0.f;
    int p = s0;
    for (; p + 2 <= s1; p += 2) {
        float4 a0 = aperm[p];
        float4 a1 = aperm[p + 1];
        int sj0 = __float_as_int(a0.w);
        int sj1 = __float_as_int(a1.w);
        float zz0 = z[sj0 * HD + c];
        float zz1 = z[sj1 * HD + c];
        float ea0 = fmaf(a0.x, w0, fmaf(a0.y, w1, fmaf(a0.z, w2, bb)));
        float ea1 = fmaf(a1.x, w0, fmaf(a1.y, w1, fmaf(a1.z, w2, bb)));
        float m0 = fmaxf(zz0 + ea0, 0.f) + MSG_EPS;
        float m1 = fmaxf(zz1 + ea1, 0.f) + MSG_EPS;
        float e0 = __expf(tv * m0);
        float e1 = __expf(tv * m1);
        num += e0 + e1;
        wm = fmaf(m0, e0, fmaf(m1, e1, wm));
    }
    if (p < s1) {
        float4 a = aperm[p];
        int sj = __float_as_int(a.w);
        float ea = fmaf(a.x, w0, fmaf(a.y, w1, fmaf(a.z, w2, bb)));
        float msg = fmaxf(z[sj * HD + c] + ea, 0.f) + MSG_EPS;
        float ex = __expf(tv * msg);
        num += ex;
        wm = fmaf(msg, ex, wm);
    }
    float agg = (s1 > s0) ? (wm / num) : 0.f;
    outb[n * HD + c] = agg + z[n * HD + c];
}

// ---------------- fused MFMA MLP ----------------
// y = relu(LN(A@W1+b1)) @ W2 + b2 ; h = (add? h+y : y)
// block: 256 threads (4 waves), BM=64 nodes.
// GEMM1: 64x256, K=128 : wave w owns cols w*64..w*64+63 (4 col-tiles) x 4 row-tiles
// GEMM2: 64x128, K=256 : wave w owns cols w*32..w*32+31 (2 col-tiles) x 4 row-tiles
#define BM 64
#define AS_LD 136   // 128 + 8 bf16 pad: row stride 68 words -> 4-bank shift -> free 2-way
#define HS_LD 264   // 256 + 8 bf16 pad

__global__ __launch_bounds__(256) void k_mlp(const float* __restrict__ outb,
                                             const unsigned short* __restrict__ W1T,
                                             const float* __restrict__ b1l,
                                             const float* __restrict__ lgl,
                                             const float* __restrict__ lbl,
                                             const unsigned short* __restrict__ W2T,
                                             const float* __restrict__ b2l,
                                             float* __restrict__ h, int add_residual) {
    __shared__ __align__(16) unsigned short As[BM * AS_LD];  // 17408 B
    __shared__ __align__(16) unsigned short Hs[BM * HS_LD];  // 33792 B

    int nb = blockIdx.x * BM;
    int tid = threadIdx.x;
    int w = tid >> 6, lane = tid & 63, q = lane >> 4, i = lane & 15;

    // ---- stage A tile (fp32 -> bf16) ----
    const float4* outb4 = (const float4*)outb;
    for (int idx = tid; idx < BM * 32; idx += 256) {
        int r = idx >> 5, c4 = idx & 31;
        int row = nb + r;
        float4 v = make_float4(0.f, 0.f, 0.f, 0.f);
        if (row < NN) v = outb4[row * 32 + c4];
        ushort4 o;
        o.x = f2b(v.x); o.y = f2b(v.y); o.z = f2b(v.z); o.w = f2b(v.w);
        *(ushort4*)&As[r * AS_LD + c4 * 4] = o;
    }
    __syncthreads();

    // ---- GEMM1: acc[rt][ctl] = A(16 rows) x W1(16 cols), K=128 ----
    f32x4 acc[4][4];
#pragma unroll
    for (int rt = 0; rt < 4; rt++)
#pragma unroll
        for (int ct = 0; ct < 4; ct++) acc[rt][ct] = (f32x4){0.f, 0.f, 0.f, 0.f};

#pragma unroll
    for (int ks = 0; ks < 4; ks++) {
        bf16x8 af[4], bf[4];
#pragma unroll
        for (int rt = 0; rt < 4; rt++)
            af[rt] = *(const bf16x8*)&As[(rt * 16 + i) * AS_LD + ks * 32 + q * 8];
#pragma unroll
        for (int ct = 0; ct < 4; ct++)
            bf[ct] = *(const bf16x8*)&W1T[(w * 64 + ct * 16 + i) * HD + ks * 32 + q * 8];
#pragma unroll
        for (int rt = 0; rt < 4; rt++)
#pragma unroll
            for (int ct = 0; ct < 4; ct++)
                acc[rt][ct] = __builtin_amdgcn_mfma_f32_16x16x32_bf16(af[rt], bf[ct],
                                                                     acc[rt][ct], 0, 0, 0);
    }

    // ---- +b1, round to bf16 into Hs (C-layout: row = rt*16+q*4+reg, col = w*64+ct*16+i) ----
    float b1c[4];
#pragma unroll
    for (int ct = 0; ct < 4; ct++) b1c[ct] = b1l[w * 64 + ct * 16 + i];
#pragma unroll
    for (int rt = 0; rt < 4; rt++)
#pragma unroll
        for (int ct = 0; ct < 4; ct++)
#pragma unroll
            for (int r = 0; r < 4; r++)
                Hs[(rt * 16 + q * 4 + r) * HS_LD + w * 64 + ct * 16 + i] =
                    f2b(acc[rt][ct][r] + b1c[ct]);
    __syncthreads();

    // ---- LN(256)+relu on Hs (bf16 in/out, fp32 stats); wave w handles rows w*16..+15 ----
    {
        float4 g4 = *(const float4*)&lgl[lane * 4];
        float4 be4 = *(const float4*)&lbl[lane * 4];
        for (int r = 0; r < 16; r++) {
            int row = w * 16 + r;
            ushort4 hv = *(ushort4*)&Hs[row * HS_LD + lane * 4];
            float v0 = b2f(hv.x), v1 = b2f(hv.y), v2 = b2f(hv.z), v3 = b2f(hv.w);
            float s = v0 + v1 + v2 + v3;
            float sq = v0 * v0 + v1 * v1 + v2 * v2 + v3 * v3;
#pragma unroll
            for (int m = 32; m >= 1; m >>= 1) {
                s += __shfl_xor(s, m);
                sq += __shfl_xor(sq, m);
            }
            float mu = s * (1.f / 256.f);
            float var = sq * (1.f / 256.f) - mu * mu;
            float inv = rsqrtf(var + LNEPS);
            ushort4 o;
            o.x = f2b(fmaxf(fmaf((v0 - mu) * inv, g4.x, be4.x), 0.f));
            o.y = f2b(fmaxf(fmaf((v1 - mu) * inv, g4.y, be4.y), 0.f));
            o.z = f2b(fmaxf(fmaf((v2 - mu) * inv, g4.z, be4.z), 0.f));
            o.w = f2b(fmaxf(fmaf((v3 - mu) * inv, g4.w, be4.w), 0.f));
            *(ushort4*)&Hs[row * HS_LD + lane * 4] = o;
        }
    }
    __syncthreads();

    // ---- GEMM2: 64x128, K=256 ----
    f32x4 acc2[4][2];
#pragma unroll
    for (int rt = 0; rt < 4; rt++)
#pragma unroll
        for (int ct = 0; ct < 2; ct++) acc2[rt][ct] = (f32x4){0.f, 0.f, 0.f, 0.f};

#pragma unroll
    for (int ks = 0; ks < 8; ks++) {
        bf16x8 af[4], bf[2];
#pragma unroll
        for (int rt = 0; rt < 4; rt++)
            af[rt] = *(const bf16x8*)&Hs[(rt * 16 + i) * HS_LD + ks * 32 + q * 8];
#pragma unroll
        for (int ct = 0; ct < 2; ct++)
            bf[ct] = *(const bf16x8*)&W2T[(w * 32 + ct * 16 + i) * HD2 + ks * 32 + q * 8];
#pragma unroll
        for (int rt = 0; rt < 4; rt++)
#pragma unroll
            for (int ct = 0; ct < 2; ct++)
                acc2[rt][ct] = __builtin_amdgcn_mfma_f32_16x16x32_bf16(af[rt], bf[ct],
                                                                      acc2[rt][ct], 0, 0, 0);
    }

    float b2c[2];
#pragma unroll
    for (int ct = 0; ct < 2; ct++) b2c[ct] = b2l[w * 32 + ct * 16 + i];
#pragma unroll
    for (int rt = 0; rt < 4; rt++)
#pragma unroll
        for (int ct = 0; ct < 2; ct++)
#pragma unroll
            for (int r = 0; r < 4; r++) {
                int row = nb + rt * 16 + q * 4 + r;
                if (row < NN) {
                    size_t idx = (size_t)row * HD + w * 32 + ct * 16 + i;
                    float v = acc2[rt][ct][r] + b2c[ct];
                    h[idx] = add_residual ? (h[idx] + v) : v;
                }
            }
}

// ---------------- global mean pool ----------------
__global__ void k_pool_accum(const float* __restrict__ z, const int* __restrict__ batch,
                             float* __restrict__ sums, float* __restrict__ cnt) {
    int n = blockIdx.x;
    int c = threadIdx.x;
    int g = batch[n];
    atomicAdd(&sums[g * HD + c], z[n * HD + c]);
    if (c == 0) atomicAdd(&cnt[g], 1.0f);
}

__global__ void k_pool_final(const float* __restrict__ sums, const float* __restrict__ cnt,
                             float* __restrict__ out) {
    int g = blockIdx.x;
    int c = threadIdx.x;
    out[g * HD + c] = sums[g * HD + c] / fmaxf(cnt[g], 1.0f);
}

// ---------------- launch ----------------
extern "C" void kernel_launch(void* const* d_in, const int* in_sizes, int n_in, void* d_out,
                              int out_size, void* d_ws, size_t ws_size, hipStream_t stream) {
    const float* x     = (const float*)d_in[0];
    const int* ei      = (const int*)d_in[1];
    const float* eattr = (const float*)d_in[2];
    const int* batch   = (const int*)d_in[3];
    const float* encW  = (const float*)d_in[4];
    const float* encB  = (const float*)d_in[5];
    const float* eW    = (const float*)d_in[6];
    const float* eB    = (const float*)d_in[7];
    const float* ln_g  = (const float*)d_in[8];
    const float* ln_b  = (const float*)d_in[9];
    const float* W1    = (const float*)d_in[10];
    const float* b1    = (const float*)d_in[11];
    const float* mlg   = (const float*)d_in[12];
    const float* mlb   = (const float*)d_in[13];
    const float* W2    = (const float*)d_in[14];
    const float* b2    = (const float*)d_in[15];
    const float* t     = (const float*)d_in[16];
    const int* src = ei;
    const int* dst = ei + NE;

    char* w = (char*)d_ws;
    auto alloc = [&](size_t bytes) {
        char* p = w;
        w += (bytes + 255) & ~size_t(255);
        return p;
    };
    float* h        = (float*)alloc(sizeof(float) * NN * HD);
    float* z        = (float*)alloc(sizeof(float) * NN * HD);
    float* outb     = (float*)alloc(sizeof(float) * NN * HD);
    float4* aperm   = (float4*)alloc(sizeof(float4) * NE);
    int* row_start  = (int*)alloc(sizeof(int) * (NN + 1));
    int* counts     = (int*)alloc(sizeof(int) * NN);
    int* cursor     = (int*)alloc(sizeof(int) * NN);
    int* incl       = (int*)alloc(sizeof(int) * NN);
    int* bsum       = (int*)alloc(sizeof(int) * 128);
    int* boff       = (int*)alloc(sizeof(int) * 128);
    float* sums     = (float*)alloc(sizeof(float) * NG * HD);
    float* cnt      = (float*)alloc(sizeof(float) * NG);
    unsigned short* W1T = (unsigned short*)alloc(sizeof(unsigned short) * NL * HD * HD2);
    unsigned short* W2T = (unsigned short*)alloc(sizeof(unsigned short) * NL * HD2 * HD);

    hipMemsetAsync(counts, 0, sizeof(int) * NN, stream);
    hipMemsetAsync(cursor, 0, sizeof(int) * NN, stream);
    hipMemsetAsync(sums, 0, sizeof(float) * NG * HD, stream);
    hipMemsetAsync(cnt, 0, sizeof(float) * NG, stream);

    k_prep<<<512, 256, 0, stream>>>(W1, W2, W1T, W2T);
    k_encode_nodes<<<NN, HD, 0, stream>>>(x, encW, encB, h);
    k_hist<<<(NE + 255) / 256, 256, 0, stream>>>(dst, counts);
    int nsb = (NN + SCAN_B - 1) / SCAN_B;
    k_scan1<<<nsb, SCAN_B, 0, stream>>>(counts, incl, bsum);
    k_scan2<<<1, 128, 0, stream>>>(bsum, boff, nsb);
    k_scan3<<<nsb, SCAN_B, 0, stream>>>(incl, boff, row_start);
    k_scatter<<<(NE + 255) / 256, 256, 0, stream>>>(src, dst, eattr, row_start, cursor, aperm);

    for (int l = 0; l < NL; l++) {
        const float* zin;
        if (l == 0) {
            zin = h;
        } else {
            k_ln_relu<<<NN / 4, 256, 0, stream>>>(h, ln_g + l * HD, ln_b + l * HD, z);
            zin = z;
        }
        k_aggregate<<<NN, HD, 0, stream>>>(zin, aperm, row_start, eW, eB, t, l, outb);
        k_mlp<<<(NN + BM - 1) / BM, 256, 0, stream>>>(outb, W1T + (size_t)l * HD * HD2,
                                                      b1 + l * HD2, mlg + l * HD2, mlb + l * HD2,
                                                      W2T + (size_t)l * HD2 * HD, b2 + l * HD, h,
                                                      l > 0);
    }
    k_ln_relu<<<NN / 4, 256, 0, stream>>>(h, ln_g, ln_b, z);  // reuses layer-0 norm
    k_pool_accum<<<NN, HD, 0, stream>>>(z, batch, sums, cnt);
    k_pool_final<<<NG, HD, 0, stream>>>(sums, cnt, (float*)d_out);
}

// Round 3
// 636.152 us; speedup vs baseline: 1.7214x; 1.1203x over previous
//
#include <hip/hip_runtime.h>

#define NN 50000
#define NE 500000
#define HD 128
#define HD2 256
#define NL 4
#define NG 1000

constexpr float MSG_EPS = 1e-7f;
constexpr float LNEPS   = 1e-5f;

typedef float  f32x4  __attribute__((ext_vector_type(4)));
typedef __bf16 bf16x8 __attribute__((ext_vector_type(8)));

__device__ __forceinline__ unsigned short f2b(float f) {
    unsigned int u = __float_as_uint(f);
    unsigned int r = u + 0x7FFFu + ((u >> 16) & 1u);
    return (unsigned short)(r >> 16);
}
__device__ __forceinline__ float b2f(unsigned short h) {
    return __uint_as_float(((unsigned int)h) << 16);
}

// ---------------- node encoder: h = x @ Wn + bn ----------------
__global__ void k_encode_nodes(const float* __restrict__ x, const float* __restrict__ W,
                               const float* __restrict__ b, float* __restrict__ h) {
    int n = blockIdx.x;
    int c = threadIdx.x;  // 128
    float xr[9];
#pragma unroll
    for (int k = 0; k < 9; k++) xr[k] = x[n * 9 + k];
    float acc = b[c];
#pragma unroll
    for (int k = 0; k < 9; k++) acc = fmaf(xr[k], W[k * HD + c], acc);
    h[n * HD + c] = acc;
}

// ---------------- weight prep: fp32 -> bf16 transposed ----------------
__global__ void k_prep(const float* __restrict__ W1, const float* __restrict__ W2,
                       unsigned short* __restrict__ W1T, unsigned short* __restrict__ W2T) {
    int idx = blockIdx.x * 256 + threadIdx.x;  // 131072 total
    {
        int k = idx & 127, n = (idx >> 7) & 255, l = idx >> 15;
        W1T[idx] = f2b(W1[(l * 128 + k) * 256 + n]);
    }
    {
        int k = idx & 255, n = (idx >> 8) & 127, l = idx >> 15;
        W2T[idx] = f2b(W2[(l * 256 + k) * 128 + n]);
    }
}

// ---------------- CSR build ----------------
__global__ void k_hist(const int* __restrict__ dst, int* __restrict__ counts) {
    int e = blockIdx.x * blockDim.x + threadIdx.x;
    if (e < NE) atomicAdd(&counts[dst[e]], 1);
}

#define SCAN_B 512
__global__ void k_scan1(const int* __restrict__ counts, int* __restrict__ incl,
                        int* __restrict__ bsum) {
    __shared__ int s[SCAN_B];
    int i = blockIdx.x * SCAN_B + threadIdx.x;
    int v = (i < NN) ? counts[i] : 0;
    s[threadIdx.x] = v;
    __syncthreads();
    for (int off = 1; off < SCAN_B; off <<= 1) {
        int t = (threadIdx.x >= off) ? s[threadIdx.x - off] : 0;
        __syncthreads();
        s[threadIdx.x] += t;
        __syncthreads();
    }
    if (i < NN) incl[i] = s[threadIdx.x];
    if (threadIdx.x == SCAN_B - 1) bsum[blockIdx.x] = s[threadIdx.x];
}

__global__ void k_scan2(const int* __restrict__ bsum, int* __restrict__ boff, int nb) {
    __shared__ int s[128];
    int v = (threadIdx.x < nb) ? bsum[threadIdx.x] : 0;
    s[threadIdx.x] = v;
    __syncthreads();
    for (int off = 1; off < 128; off <<= 1) {
        int t = (threadIdx.x >= off) ? s[threadIdx.x - off] : 0;
        __syncthreads();
        s[threadIdx.x] += t;
        __syncthreads();
    }
    if (threadIdx.x < nb) boff[threadIdx.x] = s[threadIdx.x] - v;  // exclusive
}

__global__ void k_scan3(const int* __restrict__ incl, const int* __restrict__ boff,
                        int* __restrict__ row_start) {
    int i = blockIdx.x * SCAN_B + threadIdx.x;
    if (i < NN) row_start[i + 1] = incl[i] + boff[blockIdx.x];
    if (i == 0) row_start[0] = 0;
}

// pack {attr0, attr1, attr2, src} per CSR slot
__global__ void k_scatter(const int* __restrict__ src, const int* __restrict__ dst,
                          const float* __restrict__ eattr, const int* __restrict__ row_start,
                          int* __restrict__ cursor, float4* __restrict__ aperm) {
    int e = blockIdx.x * blockDim.x + threadIdx.x;
    if (e >= NE) return;
    int d = dst[e];
    int p = row_start[d] + atomicAdd(&cursor[d], 1);
    float4 v;
    v.x = eattr[e * 3 + 0];
    v.y = eattr[e * 3 + 1];
    v.z = eattr[e * 3 + 2];
    v.w = __int_as_float(src[e]);
    aperm[p] = v;
}

// ---------------- softmax aggregation: one wave per node, lane owns 2 channels ----
__global__ __launch_bounds__(256) void k_aggregate(const float* __restrict__ z,
                                                   const float4* __restrict__ aperm,
                                                   const int* __restrict__ row_start,
                                                   const float* __restrict__ We,
                                                   const float* __restrict__ be,
                                                   const float* __restrict__ t, int layer,
                                                   float* __restrict__ outb) {
    int w = threadIdx.x >> 6, lane = threadIdx.x & 63;
    int n = blockIdx.x * 4 + w;
    if (n >= NN) return;
    int c = lane * 2;
    float2 w0 = *(const float2*)&We[c];
    float2 w1 = *(const float2*)&We[HD + c];
    float2 w2 = *(const float2*)&We[2 * HD + c];
    float2 bb = *(const float2*)&be[c];
    float tv = t[layer];
    int s0 = row_start[n], s1 = row_start[n + 1];
    float num0 = 0.f, num1 = 0.f, wm0 = 0.f, wm1 = 0.f;
    int p = s0;
    for (; p + 2 <= s1; p += 2) {
        float4 a0 = aperm[p];
        float4 a1 = aperm[p + 1];
        int sj0 = __float_as_int(a0.w);
        int sj1 = __float_as_int(a1.w);
        float2 za = *(const float2*)&z[sj0 * HD + c];
        float2 zb = *(const float2*)&z[sj1 * HD + c];
        float ea0x = fmaf(a0.x, w0.x, fmaf(a0.y, w1.x, fmaf(a0.z, w2.x, bb.x)));
        float ea0y = fmaf(a0.x, w0.y, fmaf(a0.y, w1.y, fmaf(a0.z, w2.y, bb.y)));
        float ea1x = fmaf(a1.x, w0.x, fmaf(a1.y, w1.x, fmaf(a1.z, w2.x, bb.x)));
        float ea1y = fmaf(a1.x, w0.y, fmaf(a1.y, w1.y, fmaf(a1.z, w2.y, bb.y)));
        float m0x = fmaxf(za.x + ea0x, 0.f) + MSG_EPS;
        float m0y = fmaxf(za.y + ea0y, 0.f) + MSG_EPS;
        float m1x = fmaxf(zb.x + ea1x, 0.f) + MSG_EPS;
        float m1y = fmaxf(zb.y + ea1y, 0.f) + MSG_EPS;
        float e0x = __expf(tv * m0x), e0y = __expf(tv * m0y);
        float e1x = __expf(tv * m1x), e1y = __expf(tv * m1y);
        num0 += e0x + e1x;
        num1 += e0y + e1y;
        wm0 = fmaf(m0x, e0x, fmaf(m1x, e1x, wm0));
        wm1 = fmaf(m0y, e0y, fmaf(m1y, e1y, wm1));
    }
    if (p < s1) {
        float4 a = aperm[p];
        int sj = __float_as_int(a.w);
        float2 za = *(const float2*)&z[sj * HD + c];
        float eax = fmaf(a.x, w0.x, fmaf(a.y, w1.x, fmaf(a.z, w2.x, bb.x)));
        float eay = fmaf(a.x, w0.y, fmaf(a.y, w1.y, fmaf(a.z, w2.y, bb.y)));
        float mx = fmaxf(za.x + eax, 0.f) + MSG_EPS;
        float my = fmaxf(za.y + eay, 0.f) + MSG_EPS;
        float ex = __expf(tv * mx), ey = __expf(tv * my);
        num0 += ex;
        num1 += ey;
        wm0 = fmaf(mx, ex, wm0);
        wm1 = fmaf(my, ey, wm1);
    }
    float2 zn = *(const float2*)&z[n * HD + c];
    float2 o;
    o.x = ((s1 > s0) ? (wm0 / num0) : 0.f) + zn.x;
    o.y = ((s1 > s0) ? (wm1 / num1) : 0.f) + zn.y;
    *(float2*)&outb[n * HD + c] = o;
}

// ---------------- fused MFMA MLP + next-layer LN+relu ----------------
// hnew = (add? h : 0) + relu(LN(A@W1+b1))@W2+b2 ;  h = hnew ; z = relu(LN_next(hnew))
#define BM 64
#define AS_LD 136   // bf16 row stride (128+8): 4-bank shift -> free 2-way
#define HS_LD 264   // bf16 row stride (256+8); as fp32: stride 132

__global__ __launch_bounds__(256) void k_mlp(const float* __restrict__ outb,
                                             const unsigned short* __restrict__ W1T,
                                             const float* __restrict__ b1l,
                                             const float* __restrict__ lgl,
                                             const float* __restrict__ lbl,
                                             const unsigned short* __restrict__ W2T,
                                             const float* __restrict__ b2l,
                                             float* __restrict__ h,
                                             const float* __restrict__ gn,
                                             const float* __restrict__ bn,
                                             float* __restrict__ zout, int add_residual) {
    __shared__ __align__(16) unsigned short As[BM * AS_LD];  // 17408 B
    __shared__ __align__(16) unsigned short Hs[BM * HS_LD];  // 33792 B

    int nb = blockIdx.x * BM;
    int tid = threadIdx.x;
    int w = tid >> 6, lane = tid & 63, q = lane >> 4, i = lane & 15;

    // ---- stage A tile (fp32 -> bf16) ----
    const float4* outb4 = (const float4*)outb;
    for (int idx = tid; idx < BM * 32; idx += 256) {
        int r = idx >> 5, c4 = idx & 31;
        int row = nb + r;
        float4 v = make_float4(0.f, 0.f, 0.f, 0.f);
        if (row < NN) v = outb4[row * 32 + c4];
        ushort4 o;
        o.x = f2b(v.x); o.y = f2b(v.y); o.z = f2b(v.z); o.w = f2b(v.w);
        *(ushort4*)&As[r * AS_LD + c4 * 4] = o;
    }
    __syncthreads();

    // ---- GEMM1: 64x256, K=128 ----
    f32x4 acc[4][4];
#pragma unroll
    for (int rt = 0; rt < 4; rt++)
#pragma unroll
        for (int ct = 0; ct < 4; ct++) acc[rt][ct] = (f32x4){0.f, 0.f, 0.f, 0.f};

#pragma unroll
    for (int ks = 0; ks < 4; ks++) {
        bf16x8 af[4], bf[4];
#pragma unroll
        for (int rt = 0; rt < 4; rt++)
            af[rt] = *(const bf16x8*)&As[(rt * 16 + i) * AS_LD + ks * 32 + q * 8];
#pragma unroll
        for (int ct = 0; ct < 4; ct++)
            bf[ct] = *(const bf16x8*)&W1T[(w * 64 + ct * 16 + i) * HD + ks * 32 + q * 8];
#pragma unroll
        for (int rt = 0; rt < 4; rt++)
#pragma unroll
            for (int ct = 0; ct < 4; ct++)
                acc[rt][ct] = __builtin_amdgcn_mfma_f32_16x16x32_bf16(af[rt], bf[ct],
                                                                     acc[rt][ct], 0, 0, 0);
    }

    // ---- +b1, round to bf16 into Hs (C-layout: row=rt*16+q*4+r, col=w*64+ct*16+i) ----
    float b1c[4];
#pragma unroll
    for (int ct = 0; ct < 4; ct++) b1c[ct] = b1l[w * 64 + ct * 16 + i];
#pragma unroll
    for (int rt = 0; rt < 4; rt++)
#pragma unroll
        for (int ct = 0; ct < 4; ct++)
#pragma unroll
            for (int r = 0; r < 4; r++)
                Hs[(rt * 16 + q * 4 + r) * HS_LD + w * 64 + ct * 16 + i] =
                    f2b(acc[rt][ct][r] + b1c[ct]);
    __syncthreads();

    // ---- LN(256)+relu on Hs (bf16 in/out, fp32 stats); wave w: rows w*16..+15 ----
    {
        float4 g4 = *(const float4*)&lgl[lane * 4];
        float4 be4 = *(const float4*)&lbl[lane * 4];
        for (int r = 0; r < 16; r++) {
            int row = w * 16 + r;
            ushort4 hv = *(ushort4*)&Hs[row * HS_LD + lane * 4];
            float v0 = b2f(hv.x), v1 = b2f(hv.y), v2 = b2f(hv.z), v3 = b2f(hv.w);
            float s = v0 + v1 + v2 + v3;
            float sq = v0 * v0 + v1 * v1 + v2 * v2 + v3 * v3;
#pragma unroll
            for (int m = 32; m >= 1; m >>= 1) {
                s += __shfl_xor(s, m);
                sq += __shfl_xor(sq, m);
            }
            float mu = s * (1.f / 256.f);
            float var = sq * (1.f / 256.f) - mu * mu;
            float inv = rsqrtf(var + LNEPS);
            ushort4 o;
            o.x = f2b(fmaxf(fmaf((v0 - mu) * inv, g4.x, be4.x), 0.f));
            o.y = f2b(fmaxf(fmaf((v1 - mu) * inv, g4.y, be4.y), 0.f));
            o.z = f2b(fmaxf(fmaf((v2 - mu) * inv, g4.z, be4.z), 0.f));
            o.w = f2b(fmaxf(fmaf((v3 - mu) * inv, g4.w, be4.w), 0.f));
            *(ushort4*)&Hs[row * HS_LD + lane * 4] = o;
        }
    }
    __syncthreads();

    // ---- GEMM2: 64x128, K=256 ----
    f32x4 acc2[4][2];
#pragma unroll
    for (int rt = 0; rt < 4; rt++)
#pragma unroll
        for (int ct = 0; ct < 2; ct++) acc2[rt][ct] = (f32x4){0.f, 0.f, 0.f, 0.f};

#pragma unroll
    for (int ks = 0; ks < 8; ks++) {
        bf16x8 af[4], bf[2];
#pragma unroll
        for (int rt = 0; rt < 4; rt++)
            af[rt] = *(const bf16x8*)&Hs[(rt * 16 + i) * HS_LD + ks * 32 + q * 8];
#pragma unroll
        for (int ct = 0; ct < 2; ct++)
            bf[ct] = *(const bf16x8*)&W2T[(w * 32 + ct * 16 + i) * HD2 + ks * 32 + q * 8];
#pragma unroll
        for (int rt = 0; rt < 4; rt++)
#pragma unroll
            for (int ct = 0; ct < 2; ct++)
                acc2[rt][ct] = __builtin_amdgcn_mfma_f32_16x16x32_bf16(af[rt], bf[ct],
                                                                      acc2[rt][ct], 0, 0, 0);
    }
    __syncthreads();  // all waves done reading Hs; reuse as fp32 tile

    // ---- epilogue: hnew -> global h + LDS fp32 tile ----
    float* Hsf = (float*)Hs;  // row stride 132 floats
    float b2c[2];
#pragma unroll
    for (int ct = 0; ct < 2; ct++) b2c[ct] = b2l[w * 32 + ct * 16 + i];
#pragma unroll
    for (int rt = 0; rt < 4; rt++)
#pragma unroll
        for (int ct = 0; ct < 2; ct++)
#pragma unroll
            for (int r = 0; r < 4; r++) {
                int rloc = rt * 16 + q * 4 + r;
                int row = nb + rloc;
                int col = w * 32 + ct * 16 + i;
                if (row < NN) {
                    size_t idx = (size_t)row * HD + col;
                    float v = acc2[rt][ct][r] + b2c[ct];
                    float hn = add_residual ? (h[idx] + v) : v;
                    h[idx] = hn;
                    Hsf[rloc * 132 + col] = hn;
                }
            }
    __syncthreads();

    // ---- fused next-layer LN(128)+relu -> zout; wave w: rows w*16..+15 ----
    {
        float g0 = gn[lane], g1 = gn[lane + 64];
        float c0 = bn[lane], c1 = bn[lane + 64];
        for (int rr = 0; rr < 16; rr++) {
            int rloc = w * 16 + rr;
            int row = nb + rloc;
            if (row >= NN) break;
            float v0 = Hsf[rloc * 132 + lane];
            float v1 = Hsf[rloc * 132 + 64 + lane];
            float s = v0 + v1, sq = v0 * v0 + v1 * v1;
#pragma unroll
            for (int m = 32; m >= 1; m >>= 1) {
                s += __shfl_xor(s, m);
                sq += __shfl_xor(sq, m);
            }
            float mu = s * (1.f / 128.f);
            float var = sq * (1.f / 128.f) - mu * mu;
            float inv = rsqrtf(var + LNEPS);
            zout[(size_t)row * HD + lane] = fmaxf(fmaf((v0 - mu) * inv, g0, c0), 0.f);
            zout[(size_t)row * HD + 64 + lane] = fmaxf(fmaf((v1 - mu) * inv, g1, c1), 0.f);
        }
    }
}

// ---------------- atomic-free global mean pool (batch is sorted) ----------------
__global__ void k_gbounds(const int* __restrict__ batch, int* __restrict__ gstart) {
    int g = blockIdx.x * blockDim.x + threadIdx.x;
    if (g > NG) return;
    int lo = 0, hi = NN;
    while (lo < hi) {
        int mid = (lo + hi) >> 1;
        if (batch[mid] < g) lo = mid + 1;
        else hi = mid;
    }
    gstart[g] = lo;
}

__global__ void k_pool(const float* __restrict__ z, const int* __restrict__ gstart,
                       float* __restrict__ out) {
    int g = blockIdx.x;
    int c = threadIdx.x;  // 128
    int a = gstart[g], b = gstart[g + 1];
    float s0 = 0.f, s1 = 0.f;
    int n = a;
    for (; n + 2 <= b; n += 2) {
        s0 += z[(size_t)n * HD + c];
        s1 += z[(size_t)(n + 1) * HD + c];
    }
    if (n < b) s0 += z[(size_t)n * HD + c];
    out[g * HD + c] = (s0 + s1) / fmaxf((float)(b - a), 1.f);
}

// ---------------- launch ----------------
extern "C" void kernel_launch(void* const* d_in, const int* in_sizes, int n_in, void* d_out,
                              int out_size, void* d_ws, size_t ws_size, hipStream_t stream) {
    const float* x     = (const float*)d_in[0];
    const int* ei      = (const int*)d_in[1];
    const float* eattr = (const float*)d_in[2];
    const int* batch   = (const int*)d_in[3];
    const float* encW  = (const float*)d_in[4];
    const float* encB  = (const float*)d_in[5];
    const float* eW    = (const float*)d_in[6];
    const float* eB    = (const float*)d_in[7];
    const float* ln_g  = (const float*)d_in[8];
    const float* ln_b  = (const float*)d_in[9];
    const float* W1    = (const float*)d_in[10];
    const float* b1    = (const float*)d_in[11];
    const float* mlg   = (const float*)d_in[12];
    const float* mlb   = (const float*)d_in[13];
    const float* W2    = (const float*)d_in[14];
    const float* b2    = (const float*)d_in[15];
    const float* t     = (const float*)d_in[16];
    const int* src = ei;
    const int* dst = ei + NE;

    char* w = (char*)d_ws;
    auto alloc = [&](size_t bytes) {
        char* p = w;
        w += (bytes + 255) & ~size_t(255);
        return p;
    };
    float* h        = (float*)alloc(sizeof(float) * NN * HD);
    float* z        = (float*)alloc(sizeof(float) * NN * HD);
    float* outb     = (float*)alloc(sizeof(float) * NN * HD);
    float4* aperm   = (float4*)alloc(sizeof(float4) * NE);
    int* row_start  = (int*)alloc(sizeof(int) * (NN + 1));
    int* counts     = (int*)alloc(sizeof(int) * NN);
    int* cursor     = (int*)alloc(sizeof(int) * NN);
    int* incl       = (int*)alloc(sizeof(int) * NN);
    int* bsum       = (int*)alloc(sizeof(int) * 128);
    int* boff       = (int*)alloc(sizeof(int) * 128);
    int* gstart     = (int*)alloc(sizeof(int) * (NG + 1));
    unsigned short* W1T = (unsigned short*)alloc(sizeof(unsigned short) * NL * HD * HD2);
    unsigned short* W2T = (unsigned short*)alloc(sizeof(unsigned short) * NL * HD2 * HD);

    hipMemsetAsync(counts, 0, sizeof(int) * NN, stream);
    hipMemsetAsync(cursor, 0, sizeof(int) * NN, stream);

    k_prep<<<512, 256, 0, stream>>>(W1, W2, W1T, W2T);
    k_encode_nodes<<<NN, HD, 0, stream>>>(x, encW, encB, h);
    k_hist<<<(NE + 255) / 256, 256, 0, stream>>>(dst, counts);
    int nsb = (NN + SCAN_B - 1) / SCAN_B;
    k_scan1<<<nsb, SCAN_B, 0, stream>>>(counts, incl, bsum);
    k_scan2<<<1, 128, 0, stream>>>(bsum, boff, nsb);
    k_scan3<<<nsb, SCAN_B, 0, stream>>>(incl, boff, row_start);
    k_scatter<<<(NE + 255) / 256, 256, 0, stream>>>(src, dst, eattr, row_start, cursor, aperm);
    k_gbounds<<<(NG + 256) / 256, 256, 0, stream>>>(batch, gstart);

    for (int l = 0; l < NL; l++) {
        const float* zin = (l == 0) ? h : z;
        k_aggregate<<<(NN + 3) / 4, 256, 0, stream>>>(zin, aperm, row_start, eW, eB, t, l, outb);
        int ln_next = (l + 1) % NL;  // layer 3 fuses the final ln (reuses layer-0 params)
        k_mlp<<<(NN + BM - 1) / BM, 256, 0, stream>>>(
            outb, W1T + (size_t)l * HD * HD2, b1 + l * HD2, mlg + l * HD2, mlb + l * HD2,
            W2T + (size_t)l * HD2 * HD, b2 + l * HD, h, ln_g + ln_next * HD, ln_b + ln_next * HD,
            z, l > 0);
    }
    k_pool<<<NG, HD, 0, stream>>>(z, gstart, (float*)d_out);
}

// Round 4
// 558.814 us; speedup vs baseline: 1.9597x; 1.1384x over previous
//
#include <hip/hip_runtime.h>

#define NN 50000
#define NE 500000
#define HD 128
#define HD2 256
#define NL 4
#define NG 1000

constexpr float MSG_EPS = 1e-7f;
constexpr float LNEPS   = 1e-5f;

typedef float  f32x4  __attribute__((ext_vector_type(4)));
typedef __bf16 bf16x8 __attribute__((ext_vector_type(8)));

__device__ __forceinline__ unsigned short f2b(float f) {
    unsigned int u = __float_as_uint(f);
    unsigned int r = u + 0x7FFFu + ((u >> 16) & 1u);
    return (unsigned short)(r >> 16);
}
__device__ __forceinline__ float b2f(unsigned short h) {
    return __uint_as_float(((unsigned int)h) << 16);
}

// ---------------- node encoder: z0 = bf16(x @ Wn + bn) ----------------
__global__ void k_encode_nodes(const float* __restrict__ x, const float* __restrict__ W,
                               const float* __restrict__ b, unsigned short* __restrict__ zb) {
    int n = blockIdx.x;
    int c = threadIdx.x;  // 128
    float xr[9];
#pragma unroll
    for (int k = 0; k < 9; k++) xr[k] = x[n * 9 + k];
    float acc = b[c];
#pragma unroll
    for (int k = 0; k < 9; k++) acc = fmaf(xr[k], W[k * HD + c], acc);
    zb[n * HD + c] = f2b(acc);
}

// ---------------- weight prep: fp32 -> bf16 transposed ----------------
__global__ void k_prep(const float* __restrict__ W1, const float* __restrict__ W2,
                       unsigned short* __restrict__ W1T, unsigned short* __restrict__ W2T) {
    int idx = blockIdx.x * 256 + threadIdx.x;  // 131072 total
    {
        int k = idx & 127, n = (idx >> 7) & 255, l = idx >> 15;
        W1T[idx] = f2b(W1[(l * 128 + k) * 256 + n]);
    }
    {
        int k = idx & 255, n = (idx >> 8) & 127, l = idx >> 15;
        W2T[idx] = f2b(W2[(l * 256 + k) * 128 + n]);
    }
}

// ---------------- CSR build ----------------
__global__ void k_hist(const int* __restrict__ dst, int* __restrict__ counts) {
    int e = blockIdx.x * blockDim.x + threadIdx.x;
    if (e < NE) atomicAdd(&counts[dst[e]], 1);
}

#define SCAN_B 512
__global__ void k_scan1(const int* __restrict__ counts, int* __restrict__ incl,
                        int* __restrict__ bsum) {
    __shared__ int s[SCAN_B];
    int i = blockIdx.x * SCAN_B + threadIdx.x;
    int v = (i < NN) ? counts[i] : 0;
    s[threadIdx.x] = v;
    __syncthreads();
    for (int off = 1; off < SCAN_B; off <<= 1) {
        int t = (threadIdx.x >= off) ? s[threadIdx.x - off] : 0;
        __syncthreads();
        s[threadIdx.x] += t;
        __syncthreads();
    }
    if (i < NN) incl[i] = s[threadIdx.x];
    if (threadIdx.x == SCAN_B - 1) bsum[blockIdx.x] = s[threadIdx.x];
}

__global__ void k_scan2(const int* __restrict__ bsum, int* __restrict__ boff, int nb) {
    __shared__ int s[128];
    int v = (threadIdx.x < nb) ? bsum[threadIdx.x] : 0;
    s[threadIdx.x] = v;
    __syncthreads();
    for (int off = 1; off < 128; off <<= 1) {
        int t = (threadIdx.x >= off) ? s[threadIdx.x - off] : 0;
        __syncthreads();
        s[threadIdx.x] += t;
        __syncthreads();
    }
    if (threadIdx.x < nb) boff[threadIdx.x] = s[threadIdx.x] - v;  // exclusive
}

__global__ void k_scan3(const int* __restrict__ incl, const int* __restrict__ boff,
                        int* __restrict__ row_start) {
    int i = blockIdx.x * SCAN_B + threadIdx.x;
    if (i < NN) row_start[i + 1] = incl[i] + boff[blockIdx.x];
    if (i == 0) row_start[0] = 0;
}

// pack {attr0, attr1, attr2, src} per CSR slot
__global__ void k_scatter(const int* __restrict__ src, const int* __restrict__ dst,
                          const float* __restrict__ eattr, const int* __restrict__ row_start,
                          int* __restrict__ cursor, float4* __restrict__ aperm) {
    int e = blockIdx.x * blockDim.x + threadIdx.x;
    if (e >= NE) return;
    int d = dst[e];
    int p = row_start[d] + atomicAdd(&cursor[d], 1);
    float4 v;
    v.x = eattr[e * 3 + 0];
    v.y = eattr[e * 3 + 1];
    v.z = eattr[e * 3 + 2];
    v.w = __int_as_float(src[e]);
    aperm[p] = v;
}

// ---------------- softmax aggregation: one wave per node, lane owns 2 channels ----
// z in bf16 (4B gather/lane), outb written bf16-packed.
__global__ __launch_bounds__(256) void k_aggregate(const unsigned short* __restrict__ zb,
                                                   const float4* __restrict__ aperm,
                                                   const int* __restrict__ row_start,
                                                   const float* __restrict__ We,
                                                   const float* __restrict__ be,
                                                   const float* __restrict__ t, int layer,
                                                   unsigned int* __restrict__ outb) {
    int w = threadIdx.x >> 6, lane = threadIdx.x & 63;
    int n = blockIdx.x * 4 + w;
    if (n >= NN) return;
    int c = lane * 2;
    float2 w0 = *(const float2*)&We[c];
    float2 w1 = *(const float2*)&We[HD + c];
    float2 w2 = *(const float2*)&We[2 * HD + c];
    float2 bb = *(const float2*)&be[c];
    float tv = t[layer];
    int s0 = row_start[n], s1 = row_start[n + 1];
    float num0 = 0.f, num1 = 0.f, wm0 = 0.f, wm1 = 0.f;
    const unsigned int* z32 = (const unsigned int*)zb;
    int p = s0;
    for (; p + 2 <= s1; p += 2) {
        float4 a0 = aperm[p];
        float4 a1 = aperm[p + 1];
        int sj0 = __float_as_int(a0.w);
        int sj1 = __float_as_int(a1.w);
        unsigned int za = z32[sj0 * 64 + lane];
        unsigned int zc = z32[sj1 * 64 + lane];
        float zax = b2f((unsigned short)za), zay = b2f((unsigned short)(za >> 16));
        float zcx = b2f((unsigned short)zc), zcy = b2f((unsigned short)(zc >> 16));
        float ea0x = fmaf(a0.x, w0.x, fmaf(a0.y, w1.x, fmaf(a0.z, w2.x, bb.x)));
        float ea0y = fmaf(a0.x, w0.y, fmaf(a0.y, w1.y, fmaf(a0.z, w2.y, bb.y)));
        float ea1x = fmaf(a1.x, w0.x, fmaf(a1.y, w1.x, fmaf(a1.z, w2.x, bb.x)));
        float ea1y = fmaf(a1.x, w0.y, fmaf(a1.y, w1.y, fmaf(a1.z, w2.y, bb.y)));
        float m0x = fmaxf(zax + ea0x, 0.f) + MSG_EPS;
        float m0y = fmaxf(zay + ea0y, 0.f) + MSG_EPS;
        float m1x = fmaxf(zcx + ea1x, 0.f) + MSG_EPS;
        float m1y = fmaxf(zcy + ea1y, 0.f) + MSG_EPS;
        float e0x = __expf(tv * m0x), e0y = __expf(tv * m0y);
        float e1x = __expf(tv * m1x), e1y = __expf(tv * m1y);
        num0 += e0x + e1x;
        num1 += e0y + e1y;
        wm0 = fmaf(m0x, e0x, fmaf(m1x, e1x, wm0));
        wm1 = fmaf(m0y, e0y, fmaf(m1y, e1y, wm1));
    }
    if (p < s1) {
        float4 a = aperm[p];
        int sj = __float_as_int(a.w);
        unsigned int za = z32[sj * 64 + lane];
        float zax = b2f((unsigned short)za), zay = b2f((unsigned short)(za >> 16));
        float eax = fmaf(a.x, w0.x, fmaf(a.y, w1.x, fmaf(a.z, w2.x, bb.x)));
        float eay = fmaf(a.x, w0.y, fmaf(a.y, w1.y, fmaf(a.z, w2.y, bb.y)));
        float mx = fmaxf(zax + eax, 0.f) + MSG_EPS;
        float my = fmaxf(zay + eay, 0.f) + MSG_EPS;
        float ex = __expf(tv * mx), ey = __expf(tv * my);
        num0 += ex;
        num1 += ey;
        wm0 = fmaf(mx, ex, wm0);
        wm1 = fmaf(my, ey, wm1);
    }
    unsigned int zn = z32[n * 64 + lane];
    float ox = ((s1 > s0) ? (wm0 / num0) : 0.f) + b2f((unsigned short)zn);
    float oy = ((s1 > s0) ? (wm1 / num1) : 0.f) + b2f((unsigned short)(zn >> 16));
    outb[n * 64 + lane] = (unsigned int)f2b(ox) | ((unsigned int)f2b(oy) << 16);
}

// ---------------- fused MFMA MLP + next-layer LN+relu ----------------
// hnew = (add? h : 0) + relu(LN(A@W1+b1))@W2+b2 ;  h = hnew ; zb = bf16(relu(LN_next(hnew)))
// BM=32, 256 thr, A-fragments loaded DIRECTLY from global bf16 outb (no staging LDS).
// LDS = Hs only (16.9 KB) -> 8 blocks/CU.
#define BM 32
#define HS_LD 264   // bf16 row stride (256+8); as fp32: stride 132

__global__ __launch_bounds__(256) void k_mlp(const unsigned short* __restrict__ outb,
                                             const unsigned short* __restrict__ W1T,
                                             const float* __restrict__ b1l,
                                             const float* __restrict__ lgl,
                                             const float* __restrict__ lbl,
                                             const unsigned short* __restrict__ W2T,
                                             const float* __restrict__ b2l,
                                             float* __restrict__ h,
                                             const float* __restrict__ gn,
                                             const float* __restrict__ bn,
                                             unsigned short* __restrict__ zb,
                                             int add_residual) {
    __shared__ __align__(16) unsigned short Hs[BM * HS_LD];  // 16896 B

    int nb = blockIdx.x * BM;
    int tid = threadIdx.x;
    int w = tid >> 6, lane = tid & 63, q = lane >> 4, i = lane & 15;

    // ---- GEMM1: 32x256, K=128; A direct from global bf16 ----
    f32x4 acc[2][4];
#pragma unroll
    for (int rt = 0; rt < 2; rt++)
#pragma unroll
        for (int ct = 0; ct < 4; ct++) acc[rt][ct] = (f32x4){0.f, 0.f, 0.f, 0.f};

#pragma unroll
    for (int ks = 0; ks < 4; ks++) {
        bf16x8 af[2], bf[4];
#pragma unroll
        for (int rt = 0; rt < 2; rt++) {
            int row = nb + rt * 16 + i;
            if (row < NN)
                af[rt] = *(const bf16x8*)&outb[(size_t)row * HD + ks * 32 + q * 8];
            else
                af[rt] = (bf16x8)(__bf16)0.f;
        }
#pragma unroll
        for (int ct = 0; ct < 4; ct++)
            bf[ct] = *(const bf16x8*)&W1T[(w * 64 + ct * 16 + i) * HD + ks * 32 + q * 8];
#pragma unroll
        for (int rt = 0; rt < 2; rt++)
#pragma unroll
            for (int ct = 0; ct < 4; ct++)
                acc[rt][ct] = __builtin_amdgcn_mfma_f32_16x16x32_bf16(af[rt], bf[ct],
                                                                     acc[rt][ct], 0, 0, 0);
    }

    // ---- +b1, round to bf16 into Hs (C-layout: row=rt*16+q*4+r, col=w*64+ct*16+i) ----
    float b1c[4];
#pragma unroll
    for (int ct = 0; ct < 4; ct++) b1c[ct] = b1l[w * 64 + ct * 16 + i];
#pragma unroll
    for (int rt = 0; rt < 2; rt++)
#pragma unroll
        for (int ct = 0; ct < 4; ct++)
#pragma unroll
            for (int r = 0; r < 4; r++)
                Hs[(rt * 16 + q * 4 + r) * HS_LD + w * 64 + ct * 16 + i] =
                    f2b(acc[rt][ct][r] + b1c[ct]);
    __syncthreads();

    // ---- LN(256)+relu on Hs (bf16 in/out, fp32 stats); wave w: rows w*8..+7 ----
    {
        float4 g4 = *(const float4*)&lgl[lane * 4];
        float4 be4 = *(const float4*)&lbl[lane * 4];
        for (int r = 0; r < 8; r++) {
            int row = w * 8 + r;
            ushort4 hv = *(ushort4*)&Hs[row * HS_LD + lane * 4];
            float v0 = b2f(hv.x), v1 = b2f(hv.y), v2 = b2f(hv.z), v3 = b2f(hv.w);
            float s = v0 + v1 + v2 + v3;
            float sq = v0 * v0 + v1 * v1 + v2 * v2 + v3 * v3;
#pragma unroll
            for (int m = 32; m >= 1; m >>= 1) {
                s += __shfl_xor(s, m);
                sq += __shfl_xor(sq, m);
            }
            float mu = s * (1.f / 256.f);
            float var = sq * (1.f / 256.f) - mu * mu;
            float inv = rsqrtf(var + LNEPS);
            ushort4 o;
            o.x = f2b(fmaxf(fmaf((v0 - mu) * inv, g4.x, be4.x), 0.f));
            o.y = f2b(fmaxf(fmaf((v1 - mu) * inv, g4.y, be4.y), 0.f));
            o.z = f2b(fmaxf(fmaf((v2 - mu) * inv, g4.z, be4.z), 0.f));
            o.w = f2b(fmaxf(fmaf((v3 - mu) * inv, g4.w, be4.w), 0.f));
            *(ushort4*)&Hs[row * HS_LD + lane * 4] = o;
        }
    }
    __syncthreads();

    // ---- GEMM2: 32x128, K=256 ----
    f32x4 acc2[2][2];
#pragma unroll
    for (int rt = 0; rt < 2; rt++)
#pragma unroll
        for (int ct = 0; ct < 2; ct++) acc2[rt][ct] = (f32x4){0.f, 0.f, 0.f, 0.f};

#pragma unroll
    for (int ks = 0; ks < 8; ks++) {
        bf16x8 af[2], bf[2];
#pragma unroll
        for (int rt = 0; rt < 2; rt++)
            af[rt] = *(const bf16x8*)&Hs[(rt * 16 + i) * HS_LD + ks * 32 + q * 8];
#pragma unroll
        for (int ct = 0; ct < 2; ct++)
            bf[ct] = *(const bf16x8*)&W2T[(w * 32 + ct * 16 + i) * HD2 + ks * 32 + q * 8];
#pragma unroll
        for (int rt = 0; rt < 2; rt++)
#pragma unroll
            for (int ct = 0; ct < 2; ct++)
                acc2[rt][ct] = __builtin_amdgcn_mfma_f32_16x16x32_bf16(af[rt], bf[ct],
                                                                      acc2[rt][ct], 0, 0, 0);
    }
    __syncthreads();  // all waves done reading Hs; reuse as fp32 tile

    // ---- epilogue: hnew -> global h (fp32) + LDS fp32 tile ----
    float* Hsf = (float*)Hs;  // row stride 132 floats
    float b2c[2];
#pragma unroll
    for (int ct = 0; ct < 2; ct++) b2c[ct] = b2l[w * 32 + ct * 16 + i];
#pragma unroll
    for (int rt = 0; rt < 2; rt++)
#pragma unroll
        for (int ct = 0; ct < 2; ct++)
#pragma unroll
            for (int r = 0; r < 4; r++) {
                int rloc = rt * 16 + q * 4 + r;
                int row = nb + rloc;
                int col = w * 32 + ct * 16 + i;
                if (row < NN) {
                    size_t idx = (size_t)row * HD + col;
                    float v = acc2[rt][ct][r] + b2c[ct];
                    float hn = add_residual ? (h[idx] + v) : v;
                    h[idx] = hn;
                    Hsf[rloc * 132 + col] = hn;
                }
            }
    __syncthreads();

    // ---- fused next-layer LN(128)+relu -> zb (bf16 packed); lane owns cols 2l,2l+1 ----
    {
        float2 gg = *(const float2*)&gn[lane * 2];
        float2 cc = *(const float2*)&bn[lane * 2];
        for (int rr = 0; rr < 8; rr++) {
            int rloc = w * 8 + rr;
            int row = nb + rloc;
            if (row >= NN) break;
            float2 v = *(float2*)&Hsf[rloc * 132 + lane * 2];
            float s = v.x + v.y, sq = v.x * v.x + v.y * v.y;
#pragma unroll
            for (int m = 32; m >= 1; m >>= 1) {
                s += __shfl_xor(s, m);
                sq += __shfl_xor(sq, m);
            }
            float mu = s * (1.f / 128.f);
            float var = sq * (1.f / 128.f) - mu * mu;
            float inv = rsqrtf(var + LNEPS);
            float z0 = fmaxf(fmaf((v.x - mu) * inv, gg.x, cc.x), 0.f);
            float z1 = fmaxf(fmaf((v.y - mu) * inv, gg.y, cc.y), 0.f);
            ((unsigned int*)zb)[(size_t)row * 64 + lane] =
                (unsigned int)f2b(z0) | ((unsigned int)f2b(z1) << 16);
        }
    }
}

// ---------------- atomic-free global mean pool (batch is sorted) ----------------
__global__ void k_gbounds(const int* __restrict__ batch, int* __restrict__ gstart) {
    int g = blockIdx.x * blockDim.x + threadIdx.x;
    if (g > NG) return;
    int lo = 0, hi = NN;
    while (lo < hi) {
        int mid = (lo + hi) >> 1;
        if (batch[mid] < g) lo = mid + 1;
        else hi = mid;
    }
    gstart[g] = lo;
}

__global__ void k_pool(const unsigned short* __restrict__ zb, const int* __restrict__ gstart,
                       float* __restrict__ out) {
    int g = blockIdx.x;
    int c = threadIdx.x;  // 128
    int a = gstart[g], b = gstart[g + 1];
    float s0 = 0.f, s1 = 0.f;
    int n = a;
    for (; n + 2 <= b; n += 2) {
        s0 += b2f(zb[(size_t)n * HD + c]);
        s1 += b2f(zb[(size_t)(n + 1) * HD + c]);
    }
    if (n < b) s0 += b2f(zb[(size_t)n * HD + c]);
    out[g * HD + c] = (s0 + s1) / fmaxf((float)(b - a), 1.f);
}

// ---------------- launch ----------------
extern "C" void kernel_launch(void* const* d_in, const int* in_sizes, int n_in, void* d_out,
                              int out_size, void* d_ws, size_t ws_size, hipStream_t stream) {
    const float* x     = (const float*)d_in[0];
    const int* ei      = (const int*)d_in[1];
    const float* eattr = (const float*)d_in[2];
    const int* batch   = (const int*)d_in[3];
    const float* encW  = (const float*)d_in[4];
    const float* encB  = (const float*)d_in[5];
    const float* eW    = (const float*)d_in[6];
    const float* eB    = (const float*)d_in[7];
    const float* ln_g  = (const float*)d_in[8];
    const float* ln_b  = (const float*)d_in[9];
    const float* W1    = (const float*)d_in[10];
    const float* b1    = (const float*)d_in[11];
    const float* mlg   = (const float*)d_in[12];
    const float* mlb   = (const float*)d_in[13];
    const float* W2    = (const float*)d_in[14];
    const float* b2    = (const float*)d_in[15];
    const float* t     = (const float*)d_in[16];
    const int* src = ei;
    const int* dst = ei + NE;

    char* w = (char*)d_ws;
    auto alloc = [&](size_t bytes) {
        char* p = w;
        w += (bytes + 255) & ~size_t(255);
        return p;
    };
    float* h             = (float*)alloc(sizeof(float) * NN * HD);
    unsigned short* zb   = (unsigned short*)alloc(sizeof(unsigned short) * NN * HD);
    unsigned int* outb   = (unsigned int*)alloc(sizeof(unsigned int) * NN * HD / 2);
    float4* aperm        = (float4*)alloc(sizeof(float4) * NE);
    int* row_start       = (int*)alloc(sizeof(int) * (NN + 1));
    int* counts          = (int*)alloc(sizeof(int) * NN);
    int* cursor          = (int*)alloc(sizeof(int) * NN);
    int* incl            = (int*)alloc(sizeof(int) * NN);
    int* bsum            = (int*)alloc(sizeof(int) * 128);
    int* boff            = (int*)alloc(sizeof(int) * 128);
    int* gstart          = (int*)alloc(sizeof(int) * (NG + 1));
    unsigned short* W1T  = (unsigned short*)alloc(sizeof(unsigned short) * NL * HD * HD2);
    unsigned short* W2T  = (unsigned short*)alloc(sizeof(unsigned short) * NL * HD2 * HD);

    hipMemsetAsync(counts, 0, sizeof(int) * NN, stream);
    hipMemsetAsync(cursor, 0, sizeof(int) * NN, stream);

    k_prep<<<512, 256, 0, stream>>>(W1, W2, W1T, W2T);
    k_encode_nodes<<<NN, HD, 0, stream>>>(x, encW, encB, zb);
    k_hist<<<(NE + 255) / 256, 256, 0, stream>>>(dst, counts);
    int nsb = (NN + SCAN_B - 1) / SCAN_B;
    k_scan1<<<nsb, SCAN_B, 0, stream>>>(counts, incl, bsum);
    k_scan2<<<1, 128, 0, stream>>>(bsum, boff, nsb);
    k_scan3<<<nsb, SCAN_B, 0, stream>>>(incl, boff, row_start);
    k_scatter<<<(NE + 255) / 256, 256, 0, stream>>>(src, dst, eattr, row_start, cursor, aperm);
    k_gbounds<<<(NG + 256) / 256, 256, 0, stream>>>(batch, gstart);

    for (int l = 0; l < NL; l++) {
        k_aggregate<<<(NN + 3) / 4, 256, 0, stream>>>(zb, aperm, row_start, eW, eB, t, l, outb);
        int ln_next = (l + 1) % NL;  // layer 3 fuses the final ln (reuses layer-0 params)
        k_mlp<<<(NN + BM - 1) / BM, 256, 0, stream>>>(
            (const unsigned short*)outb, W1T + (size_t)l * HD * HD2, b1 + l * HD2,
            mlg + l * HD2, mlb + l * HD2, W2T + (size_t)l * HD2 * HD, b2 + l * HD, h,
            ln_g + ln_next * HD, ln_b + ln_next * HD, zb, l > 0);
    }
    k_pool<<<NG, HD, 0, stream>>>(zb, gstart, (float*)d_out);
}